// Round 2
// baseline (349.715 us; speedup 1.0000x reference)
//
#include <hip/hip_runtime.h>

// MapDensePoseTex, two-stage: pure tex-transpose -> fused offsets+gather.
// tex (8,16,512,512) f32, iuv (8,3,512,512) i32, lut (24,256,256,2) f32,
// tex_res = 512. Output (8,16,512,512) f32.
//
// Round-4: prep was heterogeneous (transpose + offsets blocks interleaved)
// and ran at 3.58 TB/s (57% of achievable). Split: prep is now a pure
// streaming transpose; each gather block computes its own 1024 offsets into
// LDS (iuv/lut reads move here, offs global round-trip [16 MB] eliminated).

#define N_PARTS 24

// ---------------- transpose: 4096 blocks, one (b, ty) row each -------------
__global__ __launch_bounds__(256) void dp_transpose_kernel(
    const float* __restrict__ tex,
    float*       __restrict__ texT)
{
    constexpr int C = 16, R = 512;
    constexpr size_t plane = (size_t)R * R;
    __shared__ float lds[16 * 516];          // 33 KB, padded rows (516)

    const int tid = blockIdx.x;              // 0..4095
    const int b  = tid >> 9;
    const int ty = tid & 511;
    const float* src = tex + (size_t)b * C * plane + (size_t)ty * R;
    const int t = threadIdx.x;

    #pragma unroll
    for (int k = 0; k < 8; ++k) {
        const int f  = k * 256 + t;          // float4 id, 0..2047
        const int c  = f >> 7;               // 128 float4 per channel row
        const int x4 = f & 127;
        const float4 v = *(const float4*)(src + (size_t)c * plane + x4 * 4);
        *(float4*)&lds[c * 516 + x4 * 4] = v;   // lane-contiguous b128
    }
    __syncthreads();
    float* dst = texT + ((size_t)b * plane + (size_t)ty * R) * C;
    #pragma unroll
    for (int k = 0; k < 8; ++k) {
        const int f  = k * 256 + t;          // float4 id over (x, c-quad)
        const int x  = f >> 2;
        const int c0 = (f & 3) * 4;
        float4 v;
        v.x = lds[(c0 + 0) * 516 + x];       // pad 516 -> <=2-way conflicts
        v.y = lds[(c0 + 1) * 516 + x];
        v.z = lds[(c0 + 2) * 516 + x];
        v.w = lds[(c0 + 3) * 516 + x];
        *(float4*)(dst + (size_t)f * 4) = v; // 1 KB/wave contiguous
    }
}

// ---------------- gather: 2048 blocks, 1024 px/block, offsets fused --------
__global__ __launch_bounds__(256) void dp_gatherT_kernel(
    const float* __restrict__ texT,
    const int*   __restrict__ iuv,
    const float* __restrict__ lut,
    float*       __restrict__ out)
{
    constexpr int C = 16, R = 512;
    constexpr size_t HW = 512 * 512;
    __shared__ float lds[16 * 256];          // 16 KB tile: [c][pixel]
    __shared__ int   offs_lds[1024];         //  4 KB: this block's offsets

    const int b     = blockIdx.x & 7;        // XCD round-robin: batch per XCD
    const int inner = blockIdx.x >> 3;       // 0..255
    const int base  = inner * 1024;
    const int t = threadIdx.x;

    // ---- phase 0: compute 4 offsets/thread (round-2 math, exact) ----------
    {
        const float scale = (float)(R - 1);
        const int pix4 = base + 4 * t;
        const size_t ibase = (size_t)b * 3 * HW + pix4;
        const int4 p4 = *(const int4*)(iuv + ibase);
        const int4 u4 = *(const int4*)(iuv + ibase + HW);
        const int4 v4 = *(const int4*)(iuv + ibase + 2 * HW);

        const int parts[4] = {p4.x, p4.y, p4.z, p4.w};
        const int us[4]    = {u4.x, u4.y, u4.z, u4.w};
        const int vs[4]    = {v4.x, v4.y, v4.z, v4.w};

        int4 o4; int* o = &o4.x;
        #pragma unroll
        for (int j = 0; j < 4; ++j) {
            int i = parts[j] - 1;
            i = i < 0 ? 0 : (i > N_PARTS - 1 ? N_PARTS - 1 : i);
            // Faithful to reference: f32 divide, clip, *255, round-half-even.
            const float fu = fminf(fmaxf((float)us[j] / 255.0f, 0.0f), 1.0f);
            const float fv = fminf(fmaxf((float)vs[j] / 255.0f, 0.0f), 1.0f);
            const int ui = (int)rintf(fu * 255.0f);
            const int vi = (int)rintf(fv * 255.0f);
            const float2 s = *(const float2*)(lut + (((size_t)i * 256 + vi) * 256 + ui) * 2);
            const int uI = (int)rintf(s.x * scale);
            const int vI = (int)rintf((1.0f - s.y) * scale);
            o[j] = (parts[j] > 0) ? (vI * R + uI) : -1;
        }
        *(int4*)&offs_lds[4 * t] = o4;
    }
    __syncthreads();

    const float* tb   = texT + (size_t)b * HW * C;
    float*       outb = out  + (size_t)b * C * HW + base;

    for (int tile = 0; tile < 4; ++tile) {
        const int p = tile * 256 + t;
        const int o = offs_lds[p];           // LDS, conflict-free
        const bool m = o >= 0;
        const float4* src = (const float4*)(tb + (size_t)(m ? o : 0) * C);
        float4 r0 = src[0];                  // all four hit the SAME 64B line
        float4 r1 = src[1];
        float4 r2 = src[2];
        float4 r3 = src[3];
        if (!m) {
            r0 = r1 = r2 = r3 = make_float4(0.f, 0.f, 0.f, 0.f);
        }

        if (tile) __syncthreads();           // prior tile's LDS reads done
        lds[ 0 * 256 + t] = r0.x;  lds[ 1 * 256 + t] = r0.y;
        lds[ 2 * 256 + t] = r0.z;  lds[ 3 * 256 + t] = r0.w;
        lds[ 4 * 256 + t] = r1.x;  lds[ 5 * 256 + t] = r1.y;
        lds[ 6 * 256 + t] = r1.z;  lds[ 7 * 256 + t] = r1.w;
        lds[ 8 * 256 + t] = r2.x;  lds[ 9 * 256 + t] = r2.y;
        lds[10 * 256 + t] = r2.z;  lds[11 * 256 + t] = r2.w;
        lds[12 * 256 + t] = r3.x;  lds[13 * 256 + t] = r3.y;
        lds[14 * 256 + t] = r3.z;  lds[15 * 256 + t] = r3.w;
        __syncthreads();

        #pragma unroll
        for (int k = 0; k < 4; ++k) {
            const int idx = k * 256 + t;     // float4 id in (c, p4)
            const int c   = idx >> 6;
            const int p4  = idx & 63;
            const float4 v = *(const float4*)&lds[c * 256 + p4 * 4]; // b128
            *(float4*)(outb + (size_t)c * HW + tile * 256 + p4 * 4) = v;
        }
    }
}

// ---------------- fallback kernels (round-2 path) --------------------------
__global__ __launch_bounds__(256) void dp_offsets_kernel(
    const int*   __restrict__ iuv,
    const float* __restrict__ lut,
    int*         __restrict__ offs,
    int R)
{
    constexpr int H = 512, W = 512;
    const float scale = (float)(R - 1);
    const size_t hw = (size_t)H * W;
    const int t = blockIdx.x * blockDim.x + threadIdx.x;
    const int pix4 = t * 4;
    const int b = pix4 >> 18;
    const int p = pix4 & (int)(hw - 1);

    const size_t ibase = (size_t)b * 3 * hw + p;
    const int4 p4 = *(const int4*)(iuv + ibase);
    const int4 u4 = *(const int4*)(iuv + ibase + hw);
    const int4 v4 = *(const int4*)(iuv + ibase + 2 * hw);

    const int parts[4] = {p4.x, p4.y, p4.z, p4.w};
    const int us[4]    = {u4.x, u4.y, u4.z, u4.w};
    const int vs[4]    = {v4.x, v4.y, v4.z, v4.w};

    int4 o4; int* o = &o4.x;
    #pragma unroll
    for (int j = 0; j < 4; ++j) {
        int i = parts[j] - 1;
        i = i < 0 ? 0 : (i > N_PARTS - 1 ? N_PARTS - 1 : i);
        const float fu = fminf(fmaxf((float)us[j] / 255.0f, 0.0f), 1.0f);
        const float fv = fminf(fmaxf((float)vs[j] / 255.0f, 0.0f), 1.0f);
        const int ui = (int)rintf(fu * 255.0f);
        const int vi = (int)rintf(fv * 255.0f);
        const float2 s = *(const float2*)(lut + (((size_t)i * 256 + vi) * 256 + ui) * 2);
        const int uI = (int)rintf(s.x * scale);
        const int vI = (int)rintf((1.0f - s.y) * scale);
        o[j] = (parts[j] > 0) ? (vI * R + uI) : -1;
    }
    *(int4*)(offs + (size_t)b * hw + p) = o4;
}

__global__ __launch_bounds__(256) void dp_gather_kernel(
    const float* __restrict__ tex,
    const int*   __restrict__ offs,
    float*       __restrict__ out,
    int R)
{
    constexpr int C = 16, H = 512, W = 512;
    const size_t hw    = (size_t)H * W;
    const size_t plane = (size_t)R * R;

    const int bid  = blockIdx.x;
    const int xcd  = bid & 7;
    const int slot = bid >> 3;
    const int pl_local = slot >> 8;
    const int inner    = slot & 255;
    const int pidx = xcd * 16 + pl_local;
    const int b = pidx >> 4;
    const int c = pidx & 15;

    const int px = inner * 1024 + threadIdx.x * 4;

    const int4 o4 = *(const int4*)(offs + (size_t)b * hw + px);
    const float* tc = tex + ((size_t)b * C + c) * plane;

    float4 r;
    r.x = (o4.x >= 0) ? tc[o4.x] : 0.0f;
    r.y = (o4.y >= 0) ? tc[o4.y] : 0.0f;
    r.z = (o4.z >= 0) ? tc[o4.z] : 0.0f;
    r.w = (o4.w >= 0) ? tc[o4.w] : 0.0f;

    *(float4*)(out + ((size_t)b * C + c) * hw + px) = r;
}

extern "C" void kernel_launch(void* const* d_in, const int* in_sizes, int n_in,
                              void* d_out, int out_size, void* d_ws, size_t ws_size,
                              hipStream_t stream) {
    const float* tex = (const float*)d_in[0];
    const int*   iuv = (const int*)d_in[1];
    const float* lut = (const float*)d_in[2];
    float*       out = (float*)d_out;

    constexpr int B = 8, C = 16, H = 512, W = 512;
    int R = 512;
    {
        long long pe = (long long)in_sizes[0] / (B * C);
        int r = 1; while ((long long)(r + 1) * (r + 1) <= pe) ++r;
        R = r;
    }

    const size_t texT_bytes = (size_t)B * R * R * C * sizeof(float);  // 134 MB
    const size_t offs_bytes = (size_t)B * H * W * sizeof(int);        //   8 MB

    if (R == 512 && ws_size >= texT_bytes) {
        float* texT = (float*)d_ws;
        dp_transpose_kernel<<<dim3(4096), dim3(256), 0, stream>>>(tex, texT);
        dp_gatherT_kernel<<<dim3(2048), dim3(256), 0, stream>>>(
            texT, iuv, lut, out);
    } else if (ws_size >= offs_bytes) {
        int* offs = (int*)d_ws;
        dp_offsets_kernel<<<dim3(B * H * W / 4 / 256), dim3(256), 0, stream>>>(
            iuv, lut, offs, R);
        dp_gather_kernel<<<dim3(B * C * (H * W / 1024)), dim3(256), 0, stream>>>(
            tex, offs, out, R);
    }
}

// Round 3
// 346.186 us; speedup vs baseline: 1.0102x; 1.0102x over previous
//
#include <hip/hip_runtime.h>

// MapDensePoseTex, three-stage: transpose -> offsets -> windowed gather.
// tex (8,16,512,512) f32, iuv (8,3,512,512) i32, lut (24,256,256,2) f32,
// tex_res = 512. Output (8,16,512,512) f32.
//
// Round-5: R2 fused gather FETCH=229MB (texT share 181MB > touch count at
// 64B granule) -> lut thrash in L2 suspected. Un-fuse offsets (lut gets a
// quiet L2), cap gather at 2 blocks/CU (64KB LDS) so each XCD's in-flight
// pixel window (~65K px -> ~3.7MB texT lines) fits its 4MB L2, and mark all
// pure streams non-temporal so they don't evict texT/lut.

#define N_PARTS 24

typedef float v4f __attribute__((ext_vector_type(4)));
typedef int   v4i __attribute__((ext_vector_type(4)));

// ---------------- transpose: 4096 blocks, one (b, ty) row each -------------
__global__ __launch_bounds__(256) void dp_transpose_kernel(
    const float* __restrict__ tex,
    float*       __restrict__ texT)
{
    constexpr int C = 16, R = 512;
    constexpr size_t plane = (size_t)R * R;
    __shared__ float lds[16 * 516];          // 33 KB, padded rows (516)

    const int tid = blockIdx.x;              // 0..4095
    const int b  = tid >> 9;
    const int ty = tid & 511;
    const float* src = tex + (size_t)b * C * plane + (size_t)ty * R;
    const int t = threadIdx.x;

    #pragma unroll
    for (int k = 0; k < 8; ++k) {
        const int f  = k * 256 + t;          // float4 id, 0..2047
        const int c  = f >> 7;               // 128 float4 per channel row
        const int x4 = f & 127;
        const v4f v = __builtin_nontemporal_load(
            (const v4f*)(src + (size_t)c * plane + x4 * 4));
        *(v4f*)&lds[c * 516 + x4 * 4] = v;   // lane-contiguous b128
    }
    __syncthreads();
    float* dst = texT + ((size_t)b * plane + (size_t)ty * R) * C;
    #pragma unroll
    for (int k = 0; k < 8; ++k) {
        const int f  = k * 256 + t;          // float4 id over (x, c-quad)
        const int x  = f >> 2;
        const int c0 = (f & 3) * 4;
        v4f v;
        v.x = lds[(c0 + 0) * 516 + x];       // pad 516 -> <=2-way conflicts
        v.y = lds[(c0 + 1) * 516 + x];
        v.z = lds[(c0 + 2) * 516 + x];
        v.w = lds[(c0 + 3) * 516 + x];
        __builtin_nontemporal_store(v, (v4f*)(dst + (size_t)f * 4));
    }
}

// ---------------- offsets: 2048 blocks x 256 th x 4 px ---------------------
// lut (3.1MB) stays hot per-XCD; iuv is nt-streamed so it can't evict it.
__global__ __launch_bounds__(256) void dp_offsets_kernel(
    const int*   __restrict__ iuv,
    const float* __restrict__ lut,
    int*         __restrict__ offs,
    int R)
{
    constexpr int H = 512, W = 512;
    const float scale = (float)(R - 1);
    const size_t hw = (size_t)H * W;
    const int t = blockIdx.x * blockDim.x + threadIdx.x;
    const int pix4 = t * 4;
    const int b = pix4 >> 18;
    const int p = pix4 & (int)(hw - 1);

    const size_t ibase = (size_t)b * 3 * hw + p;
    const v4i p4 = __builtin_nontemporal_load((const v4i*)(iuv + ibase));
    const v4i u4 = __builtin_nontemporal_load((const v4i*)(iuv + ibase + hw));
    const v4i v4 = __builtin_nontemporal_load((const v4i*)(iuv + ibase + 2 * hw));

    const int parts[4] = {p4.x, p4.y, p4.z, p4.w};
    const int us[4]    = {u4.x, u4.y, u4.z, u4.w};
    const int vs[4]    = {v4.x, v4.y, v4.z, v4.w};

    v4i o4;
    #pragma unroll
    for (int j = 0; j < 4; ++j) {
        int i = parts[j] - 1;
        i = i < 0 ? 0 : (i > N_PARTS - 1 ? N_PARTS - 1 : i);
        // Faithful to reference: f32 divide, clip, *255, round-half-even.
        const float fu = fminf(fmaxf((float)us[j] / 255.0f, 0.0f), 1.0f);
        const float fv = fminf(fmaxf((float)vs[j] / 255.0f, 0.0f), 1.0f);
        const int ui = (int)rintf(fu * 255.0f);
        const int vi = (int)rintf(fv * 255.0f);
        const float2 s = *(const float2*)(lut + (((size_t)i * 256 + vi) * 256 + ui) * 2);
        const int uI = (int)rintf(s.x * scale);
        const int vI = (int)rintf((1.0f - s.y) * scale);
        const int o = (parts[j] > 0) ? (vI * R + uI) : -1;
        if (j == 0) o4.x = o; else if (j == 1) o4.y = o;
        else if (j == 2) o4.z = o; else o4.w = o;
    }
    __builtin_nontemporal_store(o4, (v4i*)(offs + (size_t)b * hw + p));
}

// ---------------- gather: 2048 blocks, 1024 px/block, 2 blocks/CU ----------
// Dynamic-LDS pad brings block LDS to 64KB -> 2 blocks/CU -> per-XCD pixel
// window ~65K px -> texT working set ~3.7MB, resident in the XCD's 4MB L2.
__global__ __launch_bounds__(256) void dp_gatherT_kernel(
    const float* __restrict__ texT,
    const int*   __restrict__ offs,
    float*       __restrict__ out)
{
    constexpr int C = 16;
    constexpr size_t HW = 512 * 512;
    __shared__ float lds[16 * 256];          // 16 KB tile: [c][pixel]
    extern __shared__ float occupancy_pad[]; // +44 KB at launch (unused)

    const int b     = blockIdx.x & 7;        // XCD round-robin: batch per XCD
    const int inner = blockIdx.x >> 3;       // 0..255
    const int base  = inner * 1024;

    const float* tb   = texT + (size_t)b * HW * C;
    const int*   ob   = offs + (size_t)b * HW + base;
    float*       outb = out  + (size_t)b * C * HW + base;
    const int t = threadIdx.x;

    for (int tile = 0; tile < 4; ++tile) {
        const int p = tile * 256 + t;
        const int o = __builtin_nontemporal_load(ob + p);   // coalesced
        const bool m = o >= 0;
        const v4f* src = (const v4f*)(tb + (size_t)(m ? o : 0) * C);
        v4f r0 = src[0];                     // all four hit the SAME 64B line
        v4f r1 = src[1];
        v4f r2 = src[2];
        v4f r3 = src[3];
        if (!m) {
            r0 = 0.f; r1 = 0.f; r2 = 0.f; r3 = 0.f;
        }

        if (tile) __syncthreads();           // prior tile's LDS reads done
        lds[ 0 * 256 + t] = r0.x;  lds[ 1 * 256 + t] = r0.y;
        lds[ 2 * 256 + t] = r0.z;  lds[ 3 * 256 + t] = r0.w;
        lds[ 4 * 256 + t] = r1.x;  lds[ 5 * 256 + t] = r1.y;
        lds[ 6 * 256 + t] = r1.z;  lds[ 7 * 256 + t] = r1.w;
        lds[ 8 * 256 + t] = r2.x;  lds[ 9 * 256 + t] = r2.y;
        lds[10 * 256 + t] = r2.z;  lds[11 * 256 + t] = r2.w;
        lds[12 * 256 + t] = r3.x;  lds[13 * 256 + t] = r3.y;
        lds[14 * 256 + t] = r3.z;  lds[15 * 256 + t] = r3.w;
        __syncthreads();

        #pragma unroll
        for (int k = 0; k < 4; ++k) {
            const int idx = k * 256 + t;     // float4 id in (c, p4)
            const int c   = idx >> 6;
            const int p4  = idx & 63;
            const v4f v = *(const v4f*)&lds[c * 256 + p4 * 4]; // b128, clean
            __builtin_nontemporal_store(
                v, (v4f*)(outb + (size_t)c * HW + tile * 256 + p4 * 4));
        }
    }
}

// ---------------- fallback gather (small-R path) ---------------------------
__global__ __launch_bounds__(256) void dp_gather_kernel(
    const float* __restrict__ tex,
    const int*   __restrict__ offs,
    float*       __restrict__ out,
    int R)
{
    constexpr int C = 16, H = 512, W = 512;
    const size_t hw    = (size_t)H * W;
    const size_t plane = (size_t)R * R;

    const int bid  = blockIdx.x;
    const int xcd  = bid & 7;
    const int slot = bid >> 3;
    const int pl_local = slot >> 8;
    const int inner    = slot & 255;
    const int pidx = xcd * 16 + pl_local;
    const int b = pidx >> 4;
    const int c = pidx & 15;

    const int px = inner * 1024 + threadIdx.x * 4;

    const int4 o4 = *(const int4*)(offs + (size_t)b * hw + px);
    const float* tc = tex + ((size_t)b * C + c) * plane;

    float4 r;
    r.x = (o4.x >= 0) ? tc[o4.x] : 0.0f;
    r.y = (o4.y >= 0) ? tc[o4.y] : 0.0f;
    r.z = (o4.z >= 0) ? tc[o4.z] : 0.0f;
    r.w = (o4.w >= 0) ? tc[o4.w] : 0.0f;

    *(float4*)(out + ((size_t)b * C + c) * hw + px) = r;
}

extern "C" void kernel_launch(void* const* d_in, const int* in_sizes, int n_in,
                              void* d_out, int out_size, void* d_ws, size_t ws_size,
                              hipStream_t stream) {
    const float* tex = (const float*)d_in[0];
    const int*   iuv = (const int*)d_in[1];
    const float* lut = (const float*)d_in[2];
    float*       out = (float*)d_out;

    constexpr int B = 8, C = 16, H = 512, W = 512;
    int R = 512;
    {
        long long pe = (long long)in_sizes[0] / (B * C);
        int r = 1; while ((long long)(r + 1) * (r + 1) <= pe) ++r;
        R = r;
    }

    const size_t texT_bytes = (size_t)B * R * R * C * sizeof(float);  // 134 MB
    const size_t offs_bytes = (size_t)B * H * W * sizeof(int);        //   8 MB

    if (R == 512 && ws_size >= texT_bytes + offs_bytes) {
        float* texT = (float*)d_ws;
        int*   offs = (int*)((char*)d_ws + texT_bytes);
        dp_transpose_kernel<<<dim3(4096), dim3(256), 0, stream>>>(tex, texT);
        dp_offsets_kernel<<<dim3(B * H * W / 4 / 256), dim3(256), 0, stream>>>(
            iuv, lut, offs, R);
        dp_gatherT_kernel<<<dim3(2048), dim3(256), 45056, stream>>>(
            texT, offs, out);
    } else if (ws_size >= offs_bytes) {
        int* offs = (int*)d_ws;
        dp_offsets_kernel<<<dim3(B * H * W / 4 / 256), dim3(256), 0, stream>>>(
            iuv, lut, offs, R);
        dp_gather_kernel<<<dim3(B * C * (H * W / 1024)), dim3(256), 0, stream>>>(
            tex, offs, out, R);
    }
}

// Round 4
// 338.774 us; speedup vs baseline: 1.0323x; 1.0219x over previous
//
#include <hip/hip_runtime.h>

// MapDensePoseTex, three-stage: transpose -> offsets -> windowed gather.
// tex (8,16,512,512) f32, iuv (8,3,512,512) i32, lut (24,256,256,2) f32,
// tex_res = 512. Output (8,16,512,512) f32.
//
// Round-6: R3 windowing cut gather FETCH 229->100MB but dur only 103->90us
// (2.6 TB/s, 20% occ): per-tile __syncthreads drains vmcnt(0) for all waves
// at once (barrier-drain stall), nothing covers it at 2 blocks/CU. Fix:
// wave-private LDS transpose slices (16ch x 64px, 4KB/wave) -> ZERO barriers;
// software-pipeline gathers one iteration ahead so counted vmcnt keeps loads
// in flight through the LDS consume phase. L2 window (2 blocks/CU) kept.

#define N_PARTS 24

typedef float v4f __attribute__((ext_vector_type(4)));
typedef int   v4i __attribute__((ext_vector_type(4)));

// ---------------- transpose: 4096 blocks, one (b, ty) row each -------------
__global__ __launch_bounds__(256) void dp_transpose_kernel(
    const float* __restrict__ tex,
    float*       __restrict__ texT)
{
    constexpr int C = 16, R = 512;
    constexpr size_t plane = (size_t)R * R;
    __shared__ float lds[16 * 516];          // 33 KB, padded rows (516)

    const int tid = blockIdx.x;              // 0..4095
    const int b  = tid >> 9;
    const int ty = tid & 511;
    const float* src = tex + (size_t)b * C * plane + (size_t)ty * R;
    const int t = threadIdx.x;

    #pragma unroll
    for (int k = 0; k < 8; ++k) {
        const int f  = k * 256 + t;          // float4 id, 0..2047
        const int c  = f >> 7;               // 128 float4 per channel row
        const int x4 = f & 127;
        const v4f v = __builtin_nontemporal_load(
            (const v4f*)(src + (size_t)c * plane + x4 * 4));
        *(v4f*)&lds[c * 516 + x4 * 4] = v;   // lane-contiguous b128
    }
    __syncthreads();
    float* dst = texT + ((size_t)b * plane + (size_t)ty * R) * C;
    #pragma unroll
    for (int k = 0; k < 8; ++k) {
        const int f  = k * 256 + t;          // float4 id over (x, c-quad)
        const int x  = f >> 2;
        const int c0 = (f & 3) * 4;
        v4f v;
        v.x = lds[(c0 + 0) * 516 + x];       // pad 516 -> <=2-way conflicts
        v.y = lds[(c0 + 1) * 516 + x];
        v.z = lds[(c0 + 2) * 516 + x];
        v.w = lds[(c0 + 3) * 516 + x];
        __builtin_nontemporal_store(v, (v4f*)(dst + (size_t)f * 4));
    }
}

// ---------------- offsets: 2048 blocks x 256 th x 4 px ---------------------
// lut (3.1MB) stays hot per-XCD; iuv is nt-streamed so it can't evict it.
__global__ __launch_bounds__(256) void dp_offsets_kernel(
    const int*   __restrict__ iuv,
    const float* __restrict__ lut,
    int*         __restrict__ offs,
    int R)
{
    constexpr int H = 512, W = 512;
    const float scale = (float)(R - 1);
    const size_t hw = (size_t)H * W;
    const int t = blockIdx.x * blockDim.x + threadIdx.x;
    const int pix4 = t * 4;
    const int b = pix4 >> 18;
    const int p = pix4 & (int)(hw - 1);

    const size_t ibase = (size_t)b * 3 * hw + p;
    const v4i p4 = __builtin_nontemporal_load((const v4i*)(iuv + ibase));
    const v4i u4 = __builtin_nontemporal_load((const v4i*)(iuv + ibase + hw));
    const v4i v4 = __builtin_nontemporal_load((const v4i*)(iuv + ibase + 2 * hw));

    const int parts[4] = {p4.x, p4.y, p4.z, p4.w};
    const int us[4]    = {u4.x, u4.y, u4.z, u4.w};
    const int vs[4]    = {v4.x, v4.y, v4.z, v4.w};

    v4i o4;
    #pragma unroll
    for (int j = 0; j < 4; ++j) {
        int i = parts[j] - 1;
        i = i < 0 ? 0 : (i > N_PARTS - 1 ? N_PARTS - 1 : i);
        // Faithful to reference: f32 divide, clip, *255, round-half-even.
        const float fu = fminf(fmaxf((float)us[j] / 255.0f, 0.0f), 1.0f);
        const float fv = fminf(fmaxf((float)vs[j] / 255.0f, 0.0f), 1.0f);
        const int ui = (int)rintf(fu * 255.0f);
        const int vi = (int)rintf(fv * 255.0f);
        const float2 s = *(const float2*)(lut + (((size_t)i * 256 + vi) * 256 + ui) * 2);
        const int uI = (int)rintf(s.x * scale);
        const int vI = (int)rintf((1.0f - s.y) * scale);
        const int o = (parts[j] > 0) ? (vI * R + uI) : -1;
        if (j == 0) o4.x = o; else if (j == 1) o4.y = o;
        else if (j == 2) o4.z = o; else o4.w = o;
    }
    __builtin_nontemporal_store(o4, (v4i*)(offs + (size_t)b * hw + p));
}

// ---------------- gather: 2048 blocks, 1024 px/block, barrier-free ---------
// Wave-private LDS slice (16ch x 64px = 4KB/wave): no __syncthreads at all.
// 4 iters/wave of 64 px, gathers pipelined one iteration ahead. 2 blocks/CU
// via dynamic-LDS pad keeps the per-XCD texT window (~3.7MB) L2-resident.
__global__ __launch_bounds__(256) void dp_gatherT_kernel(
    const float* __restrict__ texT,
    const int*   __restrict__ offs,
    float*       __restrict__ out)
{
    constexpr int C = 16;
    constexpr size_t HW = 512 * 512;
    __shared__ float lds[4 * 1024];          // 16 KB: 4 waves x (16c x 64px)
    extern __shared__ float occupancy_pad[]; // +44 KB at launch (unused)

    const int b     = blockIdx.x & 7;        // XCD round-robin: batch per XCD
    const int inner = blockIdx.x >> 3;       // 0..255
    const int base  = inner * 1024;

    const int t    = threadIdx.x;
    const int lane = t & 63;
    const int wv   = t >> 6;

    const float* tb   = texT + (size_t)b * HW * C;
    const int*   obw  = offs + (size_t)b * HW + base + wv * 256;
    float*       outb = out  + (size_t)b * C * HW + base + wv * 256;
    float*       wlds = lds + wv * 1024;

    // All 4 offsets up-front (breaks the o->gather addr dep off the pipeline).
    int o[4];
    #pragma unroll
    for (int i = 0; i < 4; ++i)
        o[i] = __builtin_nontemporal_load(obw + i * 64 + lane);

    // Prologue: iteration-0 gathers.
    v4f c0, c1, c2, c3;
    {
        const v4f* src = (const v4f*)(tb + (size_t)(o[0] >= 0 ? o[0] : 0) * C);
        c0 = src[0]; c1 = src[1]; c2 = src[2]; c3 = src[3];
    }

    #pragma unroll
    for (int iter = 0; iter < 4; ++iter) {
        // Issue next iteration's gathers BEFORE consuming the current one:
        // counted vmcnt keeps them in flight through the LDS phase below.
        v4f n0 = 0.f, n1 = 0.f, n2 = 0.f, n3 = 0.f;
        if (iter < 3) {
            const int on = o[iter + 1];
            const v4f* src = (const v4f*)(tb + (size_t)(on >= 0 ? on : 0) * C);
            n0 = src[0]; n1 = src[1]; n2 = src[2]; n3 = src[3];
        }

        // Consume current: mask, transpose through wave-private LDS slice.
        if (o[iter] < 0) { c0 = 0.f; c1 = 0.f; c2 = 0.f; c3 = 0.f; }
        wlds[ 0 * 64 + lane] = c0.x;  wlds[ 1 * 64 + lane] = c0.y;
        wlds[ 2 * 64 + lane] = c0.z;  wlds[ 3 * 64 + lane] = c0.w;
        wlds[ 4 * 64 + lane] = c1.x;  wlds[ 5 * 64 + lane] = c1.y;
        wlds[ 6 * 64 + lane] = c1.z;  wlds[ 7 * 64 + lane] = c1.w;
        wlds[ 8 * 64 + lane] = c2.x;  wlds[ 9 * 64 + lane] = c2.y;
        wlds[10 * 64 + lane] = c2.z;  wlds[11 * 64 + lane] = c2.w;
        wlds[12 * 64 + lane] = c3.x;  wlds[13 * 64 + lane] = c3.y;
        wlds[14 * 64 + lane] = c3.z;  wlds[15 * 64 + lane] = c3.w;
        // Same-wave RAW: compiler inserts lgkmcnt wait; no barrier needed.

        #pragma unroll
        for (int k = 0; k < 4; ++k) {
            // Linear b128 over the slice (conflict-free); float4 #f=k*64+lane
            // holds channel c = f>>4, pixels 4s..4s+3 with s = f&15.
            const v4f v = *(const v4f*)&wlds[k * 256 + lane * 4];
            const int c = k * 4 + (lane >> 4);
            const int s = lane & 15;
            __builtin_nontemporal_store(
                v, (v4f*)(outb + (size_t)c * HW + iter * 64 + s * 4));
        }

        c0 = n0; c1 = n1; c2 = n2; c3 = n3;
    }
}

// ---------------- fallback gather (small-R path) ---------------------------
__global__ __launch_bounds__(256) void dp_gather_kernel(
    const float* __restrict__ tex,
    const int*   __restrict__ offs,
    float*       __restrict__ out,
    int R)
{
    constexpr int C = 16, H = 512, W = 512;
    const size_t hw    = (size_t)H * W;
    const size_t plane = (size_t)R * R;

    const int bid  = blockIdx.x;
    const int xcd  = bid & 7;
    const int slot = bid >> 3;
    const int pl_local = slot >> 8;
    const int inner    = slot & 255;
    const int pidx = xcd * 16 + pl_local;
    const int b = pidx >> 4;
    const int c = pidx & 15;

    const int px = inner * 1024 + threadIdx.x * 4;

    const int4 o4 = *(const int4*)(offs + (size_t)b * hw + px);
    const float* tc = tex + ((size_t)b * C + c) * plane;

    float4 r;
    r.x = (o4.x >= 0) ? tc[o4.x] : 0.0f;
    r.y = (o4.y >= 0) ? tc[o4.y] : 0.0f;
    r.z = (o4.z >= 0) ? tc[o4.z] : 0.0f;
    r.w = (o4.w >= 0) ? tc[o4.w] : 0.0f;

    *(float4*)(out + ((size_t)b * C + c) * hw + px) = r;
}

extern "C" void kernel_launch(void* const* d_in, const int* in_sizes, int n_in,
                              void* d_out, int out_size, void* d_ws, size_t ws_size,
                              hipStream_t stream) {
    const float* tex = (const float*)d_in[0];
    const int*   iuv = (const int*)d_in[1];
    const float* lut = (const float*)d_in[2];
    float*       out = (float*)d_out;

    constexpr int B = 8, C = 16, H = 512, W = 512;
    int R = 512;
    {
        long long pe = (long long)in_sizes[0] / (B * C);
        int r = 1; while ((long long)(r + 1) * (r + 1) <= pe) ++r;
        R = r;
    }

    const size_t texT_bytes = (size_t)B * R * R * C * sizeof(float);  // 134 MB
    const size_t offs_bytes = (size_t)B * H * W * sizeof(int);        //   8 MB

    if (R == 512 && ws_size >= texT_bytes + offs_bytes) {
        float* texT = (float*)d_ws;
        int*   offs = (int*)((char*)d_ws + texT_bytes);
        dp_transpose_kernel<<<dim3(4096), dim3(256), 0, stream>>>(tex, texT);
        dp_offsets_kernel<<<dim3(B * H * W / 4 / 256), dim3(256), 0, stream>>>(
            iuv, lut, offs, R);
        dp_gatherT_kernel<<<dim3(2048), dim3(256), 45056, stream>>>(
            texT, offs, out);
    } else if (ws_size >= offs_bytes) {
        int* offs = (int*)d_ws;
        dp_offsets_kernel<<<dim3(B * H * W / 4 / 256), dim3(256), 0, stream>>>(
            iuv, lut, offs, R);
        dp_gather_kernel<<<dim3(B * C * (H * W / 1024)), dim3(256), 0, stream>>>(
            tex, offs, out, R);
    }
}

// Round 5
// 335.501 us; speedup vs baseline: 1.0424x; 1.0098x over previous
//
#include <hip/hip_runtime.h>

// MapDensePoseTex, three-stage: transpose -> offsets -> windowed gather.
// tex (8,16,512,512) f32, iuv (8,3,512,512) i32, lut (24,256,256,2) f32,
// tex_res = 512. Output (8,16,512,512) f32.
//
// Round-7: R4 gather was L1 request-bound: 4 independent dwordx4 per pixel =
// 33.5M line-transactions (~55us floor at 1/cyc/CU), measured 83us. Fix:
// lane-cooperative fetch -- lanes 4p..4p+3 load the 4 consecutive 16B
// quarters of pixel p's 64B texel line in ONE instruction, so the TA
// coalesces each 4-lane group into one transaction -> 1 line-request per
// pixel (4x fewer). Offsets shared via 1KB/wave LDS table (broadcast reads).
// All 16 gathers issued up-front (max MLP); zero barriers; 2 blocks/CU
// window kept (FETCH already at unique-line floor ~100MB).

#define N_PARTS 24

typedef float v4f __attribute__((ext_vector_type(4)));
typedef int   v4i __attribute__((ext_vector_type(4)));

// ---------------- transpose: 4096 blocks, one (b, ty) row each -------------
__global__ __launch_bounds__(256) void dp_transpose_kernel(
    const float* __restrict__ tex,
    float*       __restrict__ texT)
{
    constexpr int C = 16, R = 512;
    constexpr size_t plane = (size_t)R * R;
    __shared__ float lds[16 * 516];          // 33 KB, padded rows (516)

    const int tid = blockIdx.x;              // 0..4095
    const int b  = tid >> 9;
    const int ty = tid & 511;
    const float* src = tex + (size_t)b * C * plane + (size_t)ty * R;
    const int t = threadIdx.x;

    #pragma unroll
    for (int k = 0; k < 8; ++k) {
        const int f  = k * 256 + t;          // float4 id, 0..2047
        const int c  = f >> 7;               // 128 float4 per channel row
        const int x4 = f & 127;
        const v4f v = __builtin_nontemporal_load(
            (const v4f*)(src + (size_t)c * plane + x4 * 4));
        *(v4f*)&lds[c * 516 + x4 * 4] = v;   // lane-contiguous b128
    }
    __syncthreads();
    float* dst = texT + ((size_t)b * plane + (size_t)ty * R) * C;
    #pragma unroll
    for (int k = 0; k < 8; ++k) {
        const int f  = k * 256 + t;          // float4 id over (x, c-quad)
        const int x  = f >> 2;
        const int c0 = (f & 3) * 4;
        v4f v;
        v.x = lds[(c0 + 0) * 516 + x];       // pad 516 -> <=2-way conflicts
        v.y = lds[(c0 + 1) * 516 + x];
        v.z = lds[(c0 + 2) * 516 + x];
        v.w = lds[(c0 + 3) * 516 + x];
        __builtin_nontemporal_store(v, (v4f*)(dst + (size_t)f * 4));
    }
}

// ---------------- offsets: 2048 blocks x 256 th x 4 px ---------------------
// lut (3.1MB) stays hot per-XCD; iuv is nt-streamed so it can't evict it.
__global__ __launch_bounds__(256) void dp_offsets_kernel(
    const int*   __restrict__ iuv,
    const float* __restrict__ lut,
    int*         __restrict__ offs,
    int R)
{
    constexpr int H = 512, W = 512;
    const float scale = (float)(R - 1);
    const size_t hw = (size_t)H * W;
    const int t = blockIdx.x * blockDim.x + threadIdx.x;
    const int pix4 = t * 4;
    const int b = pix4 >> 18;
    const int p = pix4 & (int)(hw - 1);

    const size_t ibase = (size_t)b * 3 * hw + p;
    const v4i p4 = __builtin_nontemporal_load((const v4i*)(iuv + ibase));
    const v4i u4 = __builtin_nontemporal_load((const v4i*)(iuv + ibase + hw));
    const v4i v4 = __builtin_nontemporal_load((const v4i*)(iuv + ibase + 2 * hw));

    const int parts[4] = {p4.x, p4.y, p4.z, p4.w};
    const int us[4]    = {u4.x, u4.y, u4.z, u4.w};
    const int vs[4]    = {v4.x, v4.y, v4.z, v4.w};

    v4i o4;
    #pragma unroll
    for (int j = 0; j < 4; ++j) {
        int i = parts[j] - 1;
        i = i < 0 ? 0 : (i > N_PARTS - 1 ? N_PARTS - 1 : i);
        // Faithful to reference: f32 divide, clip, *255, round-half-even.
        const float fu = fminf(fmaxf((float)us[j] / 255.0f, 0.0f), 1.0f);
        const float fv = fminf(fmaxf((float)vs[j] / 255.0f, 0.0f), 1.0f);
        const int ui = (int)rintf(fu * 255.0f);
        const int vi = (int)rintf(fv * 255.0f);
        const float2 s = *(const float2*)(lut + (((size_t)i * 256 + vi) * 256 + ui) * 2);
        const int uI = (int)rintf(s.x * scale);
        const int vI = (int)rintf((1.0f - s.y) * scale);
        const int o = (parts[j] > 0) ? (vI * R + uI) : -1;
        if (j == 0) o4.x = o; else if (j == 1) o4.y = o;
        else if (j == 2) o4.z = o; else o4.w = o;
    }
    __builtin_nontemporal_store(o4, (v4i*)(offs + (size_t)b * hw + p));
}

// ---------------- gather: 2048 blocks, lane-cooperative lines --------------
// Per wave: 256 px in 4 iters of 64. Load instr (it,j): lanes 4p..4p+3 fetch
// the 4 quarters of pixel (it*64+j*16+p)'s 64B line -> coalesced to one
// transaction per pixel. Wave-private LDS transpose slice, zero barriers.
__global__ __launch_bounds__(256) void dp_gatherT_kernel(
    const float* __restrict__ texT,
    const int*   __restrict__ offs,
    float*       __restrict__ out)
{
    constexpr int C = 16;
    constexpr size_t HW = 512 * 512;
    __shared__ float lds[4 * 1024];          // 16 KB: 4 waves x (16c x 64px)
    __shared__ int   olds[4 * 256];          //  4 KB: 4 waves x 256 offsets
    extern __shared__ float occupancy_pad[]; // pad to 64KB -> 2 blocks/CU

    const int b     = blockIdx.x & 7;        // XCD round-robin: batch per XCD
    const int inner = blockIdx.x >> 3;       // 0..255
    const int base  = inner * 1024;

    const int t    = threadIdx.x;
    const int lane = t & 63;
    const int wv   = t >> 6;

    const float* tb   = texT + (size_t)b * HW * C;
    const int*   obw  = offs + (size_t)b * HW + base + wv * 256;
    float*       outb = out  + (size_t)b * C * HW + base + wv * 256;
    float*       wlds = lds  + wv * 1024;
    int*         wo   = olds + wv * 256;

    // Preload this wave's 256 offsets into LDS (b128 both ways, linear).
    {
        const v4i o4 = __builtin_nontemporal_load((const v4i*)(obw + lane * 4));
        *(v4i*)&wo[lane * 4] = o4;
    }
    // Same-wave RAW on LDS: compiler inserts the lgkmcnt wait.

    const int sub = lane >> 2;               // pixel id within a 16-px group
    const int q   = lane & 3;                // which 16B quarter of the line

    // Issue ALL 16 gather instructions up-front (counted vmcnt keeps them
    // in flight; consume below waits only for what it needs).
    v4f g00,g01,g02,g03, g10,g11,g12,g13, g20,g21,g22,g23, g30,g31,g32,g33;
    int o00,o01,o02,o03, o10,o11,o12,o13, o20,o21,o22,o23, o30,o31,o32,o33;
#define DP_LOAD(IT, J, GV, OV)                                               \
    {                                                                        \
        OV = wo[(IT) * 64 + (J) * 16 + sub];                                 \
        const float* s_ = tb + (size_t)(OV >= 0 ? OV : 0) * C + q * 4;       \
        GV = *(const v4f*)s_;                                                \
    }
    DP_LOAD(0,0,g00,o00) DP_LOAD(0,1,g01,o01) DP_LOAD(0,2,g02,o02) DP_LOAD(0,3,g03,o03)
    DP_LOAD(1,0,g10,o10) DP_LOAD(1,1,g11,o11) DP_LOAD(1,2,g12,o12) DP_LOAD(1,3,g13,o13)
    DP_LOAD(2,0,g20,o20) DP_LOAD(2,1,g21,o21) DP_LOAD(2,2,g22,o22) DP_LOAD(2,3,g23,o23)
    DP_LOAD(3,0,g30,o30) DP_LOAD(3,1,g31,o31) DP_LOAD(3,2,g32,o32) DP_LOAD(3,3,g33,o33)
#undef DP_LOAD

#define DP_PUT(J, GV, OV)                                                    \
    {                                                                        \
        v4f v_ = GV;                                                         \
        if (OV < 0) v_ = 0.f;                                                \
        const int px_ = (J) * 16 + sub;                                      \
        const int c0_ = q * 4;                                               \
        wlds[(c0_ + 0) * 64 + px_] = v_.x;                                   \
        wlds[(c0_ + 1) * 64 + px_] = v_.y;                                   \
        wlds[(c0_ + 2) * 64 + px_] = v_.z;                                   \
        wlds[(c0_ + 3) * 64 + px_] = v_.w;                                   \
    }
#define DP_STORE(IT)                                                         \
    _Pragma("unroll")                                                        \
    for (int k = 0; k < 4; ++k) {                                            \
        const v4f v_ = *(const v4f*)&wlds[k * 256 + lane * 4];               \
        const int c_ = k * 4 + (lane >> 4);                                  \
        const int s_ = lane & 15;                                            \
        __builtin_nontemporal_store(                                         \
            v_, (v4f*)(outb + (size_t)c_ * HW + (IT) * 64 + s_ * 4));        \
    }

    // iter 0
    DP_PUT(0,g00,o00) DP_PUT(1,g01,o01) DP_PUT(2,g02,o02) DP_PUT(3,g03,o03)
    DP_STORE(0)
    // iter 1 (same-wave WAR on wlds: DS ops retire in order within a wave)
    DP_PUT(0,g10,o10) DP_PUT(1,g11,o11) DP_PUT(2,g12,o12) DP_PUT(3,g13,o13)
    DP_STORE(1)
    // iter 2
    DP_PUT(0,g20,o20) DP_PUT(1,g21,o21) DP_PUT(2,g22,o22) DP_PUT(3,g23,o23)
    DP_STORE(2)
    // iter 3
    DP_PUT(0,g30,o30) DP_PUT(1,g31,o31) DP_PUT(2,g32,o32) DP_PUT(3,g33,o33)
    DP_STORE(3)
#undef DP_PUT
#undef DP_STORE
}

// ---------------- fallback gather (small-R path) ---------------------------
__global__ __launch_bounds__(256) void dp_gather_kernel(
    const float* __restrict__ tex,
    const int*   __restrict__ offs,
    float*       __restrict__ out,
    int R)
{
    constexpr int C = 16, H = 512, W = 512;
    const size_t hw    = (size_t)H * W;
    const size_t plane = (size_t)R * R;

    const int bid  = blockIdx.x;
    const int xcd  = bid & 7;
    const int slot = bid >> 3;
    const int pl_local = slot >> 8;
    const int inner    = slot & 255;
    const int pidx = xcd * 16 + pl_local;
    const int b = pidx >> 4;
    const int c = pidx & 15;

    const int px = inner * 1024 + threadIdx.x * 4;

    const int4 o4 = *(const int4*)(offs + (size_t)b * hw + px);
    const float* tc = tex + ((size_t)b * C + c) * plane;

    float4 r;
    r.x = (o4.x >= 0) ? tc[o4.x] : 0.0f;
    r.y = (o4.y >= 0) ? tc[o4.y] : 0.0f;
    r.z = (o4.z >= 0) ? tc[o4.z] : 0.0f;
    r.w = (o4.w >= 0) ? tc[o4.w] : 0.0f;

    *(float4*)(out + ((size_t)b * C + c) * hw + px) = r;
}

extern "C" void kernel_launch(void* const* d_in, const int* in_sizes, int n_in,
                              void* d_out, int out_size, void* d_ws, size_t ws_size,
                              hipStream_t stream) {
    const float* tex = (const float*)d_in[0];
    const int*   iuv = (const int*)d_in[1];
    const float* lut = (const float*)d_in[2];
    float*       out = (float*)d_out;

    constexpr int B = 8, C = 16, H = 512, W = 512;
    int R = 512;
    {
        long long pe = (long long)in_sizes[0] / (B * C);
        int r = 1; while ((long long)(r + 1) * (r + 1) <= pe) ++r;
        R = r;
    }

    const size_t texT_bytes = (size_t)B * R * R * C * sizeof(float);  // 134 MB
    const size_t offs_bytes = (size_t)B * H * W * sizeof(int);        //   8 MB

    if (R == 512 && ws_size >= texT_bytes + offs_bytes) {
        float* texT = (float*)d_ws;
        int*   offs = (int*)((char*)d_ws + texT_bytes);
        dp_transpose_kernel<<<dim3(4096), dim3(256), 0, stream>>>(tex, texT);
        dp_offsets_kernel<<<dim3(B * H * W / 4 / 256), dim3(256), 0, stream>>>(
            iuv, lut, offs, R);
        // static LDS = 20KB; +44KB pad -> 64KB -> 2 blocks/CU (L2 window)
        dp_gatherT_kernel<<<dim3(2048), dim3(256), 45056, stream>>>(
            texT, offs, out);
    } else if (ws_size >= offs_bytes) {
        int* offs = (int*)d_ws;
        dp_offsets_kernel<<<dim3(B * H * W / 4 / 256), dim3(256), 0, stream>>>(
            iuv, lut, offs, R);
        dp_gather_kernel<<<dim3(B * C * (H * W / 1024)), dim3(256), 0, stream>>>(
            tex, offs, out, R);
    }
}